// Round 6
// baseline (1745.553 us; speedup 1.0000x reference)
//
#include <hip/hip_runtime.h>
#include <math.h>

#define N   200000
#define E   6400000
#define IN_ 128
#define D   16
#define G   1024
#define BNEPS 1e-5f

#define BSH   8                      // 256 cols per bucket
#define BMSK  255
#define NBKT  782                    // ceil(N / 256)
#define CH    8192                   // edges per k_bin block
#define BINB  782                    // ceil(E / CH)

typedef _Float16 f16;
typedef __attribute__((ext_vector_type(8))) _Float16 f16x8;
typedef __attribute__((ext_vector_type(4))) float f32x4;

// ---------- helpers ----------
__device__ __forceinline__ unsigned f2ord(float f) {
    unsigned b = __float_as_uint(f);
    return (b & 0x80000000u) ? ~b : (b | 0x80000000u);
}
__device__ __forceinline__ float ord2f(unsigned u) {
    return __uint_as_float((u & 0x80000000u) ? (u & 0x7FFFFFFFu) : ~u);
}

// ---------- bucket histogram ----------
__global__ __launch_bounds__(256) void k_hist(const int* __restrict__ col,
                                              unsigned* __restrict__ bucketCnt) {
    __shared__ unsigned h[NBKT];
    for (int i = threadIdx.x; i < NBKT; i += 256) h[i] = 0u;
    __syncthreads();
    int stride = gridDim.x * 256;
    for (int e = blockIdx.x * 256 + threadIdx.x; e < E; e += stride)
        atomicAdd(&h[col[e] >> BSH], 1u);
    __syncthreads();
    for (int i = threadIdx.x; i < NBKT; i += 256)
        if (h[i]) atomicAdd(&bucketCnt[i], h[i]);
}

// ---------- scan bucket counts (1024-wide, 512 threads x 2 slots) ----------
__global__ __launch_bounds__(512) void k_bscan(const unsigned* __restrict__ bucketCnt,
                                               unsigned* __restrict__ bucketBase,
                                               unsigned* __restrict__ cursorB) {
    __shared__ unsigned s[1024];
    int t = threadIdx.x;
    s[t]       = (t < NBKT) ? bucketCnt[t] : 0u;
    s[t + 512] = (t + 512 < NBKT) ? bucketCnt[t + 512] : 0u;
    __syncthreads();
    for (int off = 1; off < 1024; off <<= 1) {
        unsigned v0 = (t >= off) ? s[t - off] : 0u;
        unsigned v1 = (t + 512 >= off) ? s[t + 512 - off] : 0u;
        __syncthreads();
        s[t] += v0;
        s[t + 512] += v1;
        __syncthreads();
    }
#pragma unroll
    for (int half = 0; half < 2; half++) {
        int idx = t + half * 512;
        if (idx <= NBKT) {
            unsigned excl = (idx > 0) ? s[idx - 1] : 0u;
            bucketBase[idx] = excl;
            cursorB[idx] = excl;
        }
    }
}

// ---------- phase 1: bin edges by bucket ----------
// packed record: src (18 bits) | col_low8 << 18
__global__ __launch_bounds__(512) void k_bin(const int* __restrict__ row,
                                             const int* __restrict__ col,
                                             unsigned* __restrict__ cursorB,
                                             unsigned* __restrict__ tmp) {
    __shared__ unsigned hist[1024];   // becomes lbase after scan
    __shared__ unsigned offs[1024];   // inclusive scan
    __shared__ unsigned lcur[1024];
    __shared__ unsigned gbase[1024];
    __shared__ unsigned sbuf[CH];     // 32 KB
    int tid = threadIdx.x;
    int base = blockIdx.x * CH;
    int cnt = min(CH, E - base);
    hist[tid] = 0u; hist[tid + 512] = 0u;
    __syncthreads();
    for (int i = tid; i < cnt; i += 512)
        atomicAdd(&hist[col[base + i] >> BSH], 1u);
    __syncthreads();
    offs[tid] = hist[tid];
    offs[tid + 512] = hist[tid + 512];
    __syncthreads();
    for (int off = 1; off < 1024; off <<= 1) {
        unsigned v0 = (tid >= off) ? offs[tid - off] : 0u;
        unsigned v1 = (tid + 512 >= off) ? offs[tid + 512 - off] : 0u;
        __syncthreads();
        offs[tid] += v0;
        offs[tid + 512] += v1;
        __syncthreads();
    }
#pragma unroll
    for (int half = 0; half < 2; half++) {
        int s = tid + half * 512;
        unsigned lb = (s > 0) ? offs[s - 1] : 0u;
        unsigned c0 = offs[s] - lb;
        lcur[s] = lb;
        hist[s] = lb;   // hist now holds lbase
        if (s < NBKT && c0) gbase[s] = atomicAdd(&cursorB[s], c0);
    }
    __syncthreads();
    for (int i = tid; i < cnt; i += 512) {
        int c = col[base + i];
        int r = row[base + i];
        int b = c >> BSH;
        unsigned p = atomicAdd(&lcur[b], 1u);
        sbuf[p] = (unsigned)r | ((unsigned)(c & BMSK) << 18);
    }
    __syncthreads();
    // bucket-major coalesced-run copy-out: one wave per bucket
    int wv = tid >> 6, ln = tid & 63;
    for (int b = wv; b < NBKT; b += 8) {
        unsigned l0 = hist[b], l1 = offs[b], gb = gbase[b];
        for (unsigned i2 = l0 + ln; i2 < l1; i2 += 64)
            tmp[gb + (i2 - l0)] = sbuf[i2];
    }
}

// ---------- per-bucket degree -> dis ----------
__global__ __launch_bounds__(512) void k_cdeg(const unsigned* __restrict__ bucketBase,
                                              const unsigned* __restrict__ tmp,
                                              float* __restrict__ dis) {
    __shared__ unsigned cnt[256];
    int tid = threadIdx.x;
    int b = blockIdx.x;
    unsigned s0 = bucketBase[b], s1 = bucketBase[b + 1];
    if (tid < 256) cnt[tid] = 0u;
    __syncthreads();
    for (unsigned i = s0 + tid; i < s1; i += 512) {
        unsigned rec = __builtin_nontemporal_load(tmp + i);
        atomicAdd(&cnt[rec >> 18], 1u);
    }
    __syncthreads();
    if (tid < 256) {
        int c = (b << BSH) + tid;
        if (c < N) dis[c] = rsqrtf((float)cnt[tid] + 1.0f);
    }
}

// ---------- hs1 = f16((x @ W1) * dis) via MFMA, split into two N x 8 halves ----------
__global__ __launch_bounds__(256) void k_gemm1(const float* __restrict__ x,
                                               const float* __restrict__ W1,
                                               const float* __restrict__ dis,
                                               f16* __restrict__ hsA,
                                               f16* __restrict__ hsB) {
    __shared__ f16 Wh[IN_ * D];
    int tid = threadIdx.x;
    for (int i = tid; i < IN_ * D; i += 256) Wh[i] = (f16)W1[i];
    __syncthreads();
    int lane = tid & 63;
    int wave = tid >> 6;
    int m = lane & 15, quad = lane >> 4;
    f16x8 bfrag[4];
#pragma unroll
    for (int s = 0; s < 4; s++)
#pragma unroll
        for (int jj = 0; jj < 8; jj++)
            bfrag[s][jj] = Wh[(s * 32 + quad * 8 + jj) * D + m];
    f16* outp = (m < 8) ? hsA : hsB;
    int mo = m & 7;
    int gwave = blockIdx.x * 4 + wave;
    int nwaves = gridDim.x * 4;
    const int ntiles = N / 16;
    for (int t = gwave; t < ntiles; t += nwaves) {
        int n0 = t * 16;
        const float* xrow = x + (size_t)(n0 + m) * IN_ + quad * 8;
        f32x4 acc = {0.f, 0.f, 0.f, 0.f};
#pragma unroll
        for (int s = 0; s < 4; s++) {
            float4 lo = *(const float4*)(xrow + s * 32);
            float4 hi = *(const float4*)(xrow + s * 32 + 4);
            f16x8 a;
            a[0] = (f16)lo.x; a[1] = (f16)lo.y; a[2] = (f16)lo.z; a[3] = (f16)lo.w;
            a[4] = (f16)hi.x; a[5] = (f16)hi.y; a[6] = (f16)hi.z; a[7] = (f16)hi.w;
            acc = __builtin_amdgcn_mfma_f32_16x16x32_f16(a, bfrag[s], acc, 0, 0, 0);
        }
#pragma unroll
        for (int r = 0; r < 4; r++) {
            int rowi = n0 + quad * 4 + r;
            outp[(size_t)rowi * 8 + mo] = (f16)(acc[r] * dis[rowi]);
        }
    }
}

// ---------- fused bucket aggregation + epilogue (one 8-feature half) ----------
// out_i[f] = BN(ReLU(dis_i * (hs[i] + sum_{src->i} hs[src]) + bias))  for f = h*8+k
// bn pointers pre-offset by h*8; out written at col*16 + h*8.
__global__ __launch_bounds__(512) void k_agg(const unsigned* __restrict__ bucketBase,
                                             const unsigned* __restrict__ tmp,
                                             const f16* __restrict__ hsplit,
                                             const float* __restrict__ dis,
                                             const float* __restrict__ bp,
                                             const float* __restrict__ gp,
                                             const float* __restrict__ bep,
                                             const float* __restrict__ mp,
                                             const float* __restrict__ vp,
                                             f16* __restrict__ out16,
                                             int hoff) {
    __shared__ float acc[8 * 256];    // k-major: acc[k*256 + c]
    __shared__ float scal[8], shif[8], bias[8];
    int tid = threadIdx.x;
    int b = blockIdx.x;
    unsigned s0 = bucketBase[b], s1 = bucketBase[b + 1];
    if (tid < 8) {
        float sc = gp[tid] * rsqrtf(vp[tid] + BNEPS);
        scal[tid] = sc;
        shif[tid] = bep[tid] - mp[tid] * sc;
        bias[tid] = bp[tid];
    }
    if (tid < 256) {
        int c = (b << BSH) + tid;
        if (c < N) {
            f16x8 v = *(const f16x8*)(hsplit + (size_t)c * 8);   // self seed
#pragma unroll
            for (int k = 0; k < 8; k++) acc[k * 256 + tid] = (float)v[k];
        } else {
#pragma unroll
            for (int k = 0; k < 8; k++) acc[k * 256 + tid] = 0.f;
        }
    }
    __syncthreads();
    for (unsigned i = s0 + tid; i < s1; i += 512) {
        unsigned rec = __builtin_nontemporal_load(tmp + i);
        int src = (int)(rec & 0x3FFFFu);
        int c = (int)(rec >> 18);
        f16x8 v = *(const f16x8*)(hsplit + (size_t)src * 8);
#pragma unroll
        for (int k = 0; k < 8; k++)
            atomicAdd(&acc[k * 256 + c], (float)v[k]);
    }
    __syncthreads();
    if (tid < 256) {
        int c = (b << BSH) + tid;
        if (c < N) {
            float di = dis[c];
            f16x8 o;
#pragma unroll
            for (int k = 0; k < 8; k++) {
                float tt = di * acc[k * 256 + tid] + bias[k];
                tt = fmaxf(tt, 0.f);
                o[k] = (f16)(tt * scal[k] + shif[k]);
            }
            *(f16x8*)(out16 + (size_t)c * 16 + hoff) = o;
        }
    }
}

// ---------- hs2 = f16((x1 @ W2) * dis), split halves ----------
__global__ __launch_bounds__(256) void k_x1w2(const f16* __restrict__ x1,
                                              const float* __restrict__ W2,
                                              const float* __restrict__ dis,
                                              f16* __restrict__ hsA,
                                              f16* __restrict__ hsB) {
    __shared__ float W2s[D * D];
    int tid = threadIdx.x;
    if (tid < D * D) W2s[tid] = W2[tid];
    __syncthreads();
    int i = blockIdx.x * 16 + (tid >> 4);
    int j = tid & 15;
    float xv = (float)x1[(size_t)i * 16 + j];
    float acc = 0.f;
#pragma unroll
    for (int kk = 0; kk < D; kk++) {
        float v = __shfl(xv, kk, 16);
        acc += v * W2s[kk * D + j];
    }
    f16 r = (f16)(acc * dis[i]);
    if (j < 8) hsA[(size_t)i * 8 + j] = r;
    else       hsB[(size_t)i * 8 + (j - 8)] = r;
}

// ---------- pooling ----------
__global__ __launch_bounds__(256) void k_pool(const f16* __restrict__ x2,
                                              const int* __restrict__ batch,
                                              unsigned* __restrict__ gmaxT,
                                              float* __restrict__ gsum,
                                              unsigned* __restrict__ gcnt) {
    __shared__ unsigned smax[32 * D];
    __shared__ float ssum[32 * D];
    __shared__ unsigned scnt[32];
    int tid = threadIdx.x;
    for (int s = tid; s < 32 * D; s += 256) { smax[s] = 0u; ssum[s] = 0.f; }
    if (tid < 32) scnt[tid] = 0u;
    __syncthreads();
    int n = blockIdx.x * 256 + tid;
    int g0 = batch[blockIdx.x * 256];
    if (n < N) {
        int lg = batch[n] - g0;
        const f16* xp = x2 + (size_t)n * D;
        if (lg < 32) {
            atomicAdd(&scnt[lg], 1u);
#pragma unroll
            for (int j = 0; j < D; j++) {
                float v = (float)xp[j];
                atomicMax(&smax[lg * D + j], f2ord(v));
                atomicAdd(&ssum[lg * D + j], v);
            }
        } else {
            int g = batch[n];
            atomicAdd(&gcnt[g], 1u);
#pragma unroll
            for (int j = 0; j < D; j++) {
                float v = (float)xp[j];
                atomicMax(&gmaxT[(size_t)g * D + j], f2ord(v));
                atomicAdd(&gsum[(size_t)g * D + j], v);
            }
        }
    }
    __syncthreads();
    for (int s = tid; s < 32 * D; s += 256) {
        int slot = s >> 4, j = s & 15;
        if (scnt[slot] > 0u) {
            int g = g0 + slot;
            atomicMax(&gmaxT[(size_t)g * D + j], smax[s]);
            atomicAdd(&gsum[(size_t)g * D + j], ssum[s]);
            if (j == 0) atomicAdd(&gcnt[g], scnt[slot]);
        }
    }
}

// ---------- head ----------
__global__ __launch_bounds__(256) void k_head(const unsigned* __restrict__ gmaxT,
                                              const float* __restrict__ gsum,
                                              const unsigned* __restrict__ gcnt,
                                              const float* __restrict__ Wb,
                                              const float* __restrict__ bb,
                                              const float* __restrict__ Wm,
                                              const float* __restrict__ bm,
                                              float* __restrict__ out) {
    __shared__ float Wbs[32 * 16];
    __shared__ float bbs[16], Wms[16];
    __shared__ float bm0;
    int tid = threadIdx.x;
    for (int i = tid; i < 32 * 16; i += 256) Wbs[i] = Wb[i];
    if (tid < 16) { bbs[tid] = bb[tid]; Wms[tid] = Wm[tid]; }
    if (tid == 0) bm0 = bm[0];
    __syncthreads();
    int g = blockIdx.x * 256 + tid;
    if (g >= G) return;
    float in[32];
    float inv = 1.0f / (float)gcnt[g];
#pragma unroll
    for (int j = 0; j < D; j++) {
        in[j] = ord2f(gmaxT[(size_t)g * D + j]);
        in[16 + j] = gsum[(size_t)g * D + j] * inv;
    }
    float z = bm0;
#pragma unroll
    for (int j = 0; j < 16; j++) {
        float acc = bbs[j];
#pragma unroll
        for (int k = 0; k < 32; k++) acc += in[k] * Wbs[k * 16 + j];
        acc = fmaxf(acc, 0.f);
        z += acc * Wms[j];
    }
    out[g] = 1.0f / (1.0f + expf(-z));
}

extern "C" void kernel_launch(void* const* d_in, const int* in_sizes, int n_in,
                              void* d_out, int out_size, void* d_ws, size_t ws_size,
                              hipStream_t stream) {
    const float* x   = (const float*)d_in[0];
    const int* ei    = (const int*)d_in[1];
    const int* rowp  = ei;
    const int* colp  = ei + E;
    const int* batch = (const int*)d_in[2];
    const float* W1  = (const float*)d_in[3];
    const float* b1  = (const float*)d_in[4];
    const float* g1  = (const float*)d_in[5];
    const float* be1 = (const float*)d_in[6];
    const float* m1  = (const float*)d_in[7];
    const float* v1  = (const float*)d_in[8];
    const float* W2  = (const float*)d_in[9];
    const float* b2  = (const float*)d_in[10];
    const float* g2  = (const float*)d_in[11];
    const float* be2 = (const float*)d_in[12];
    const float* m2  = (const float*)d_in[13];
    const float* v2  = (const float*)d_in[14];
    const float* Wb  = (const float*)d_in[15];
    const float* bb  = (const float*)d_in[16];
    const float* Wm  = (const float*)d_in[17];
    const float* bm  = (const float*)d_in[18];
    float* out = (float*)d_out;

    char* ws = (char*)d_ws;
    // layout (bytes):
    unsigned* tmp   = (unsigned*)(ws);               // E u32        [0, 25.6M)
    f16* hs1a  = (f16*)(ws + 25600000);              // N*8 f16 (3.2 MB)
    f16* hs1b  = (f16*)(ws + 28800000);              // N*8
    f16* hs2a  = (f16*)(ws + 32000000);              // N*8
    f16* hs2b  = (f16*)(ws + 35200000);              // N*8
    f16* x1buf = (f16*)(ws + 38400000);              // N*16 f16 (6.4 MB); x2 aliases after k_x1w2
    float* dis = (float*)(ws + 44800000);            // N f32
    unsigned* bucketCnt  = (unsigned*)(ws + 45600000);  // NBKT+1
    unsigned* bucketBase = (unsigned*)(ws + 45604096);  // NBKT+1
    unsigned* cursorB    = (unsigned*)(ws + 45608192);  // NBKT+1
    unsigned* gmaxT = (unsigned*)(ws + 45612288);    // G*D
    float*    gsum  = (float*)   (ws + 45677824);    // G*D
    unsigned* gcnt  = (unsigned*)(ws + 45743360);    // G
    f16* x2buf = x1buf;   // x1 fully consumed by k_x1w2 before layer-2 agg writes

    const int NB = (N + 255) / 256;   // 782

    hipMemsetAsync(bucketCnt, 0, (NBKT + 1) * 4, stream);
    hipMemsetAsync(gmaxT, 0, (size_t)G * D * 4, stream);
    hipMemsetAsync(gsum, 0, (size_t)G * D * 4, stream);
    hipMemsetAsync(gcnt, 0, (size_t)G * 4, stream);

    k_hist<<<1024, 256, 0, stream>>>(colp, bucketCnt);
    k_bscan<<<1, 512, 0, stream>>>(bucketCnt, bucketBase, cursorB);
    k_bin<<<BINB, 512, 0, stream>>>(rowp, colp, cursorB, tmp);
    k_cdeg<<<NBKT, 512, 0, stream>>>(bucketBase, tmp, dis);

    k_gemm1<<<512, 256, 0, stream>>>(x, W1, dis, hs1a, hs1b);

    // layer 1: two feature-half passes (each keeps a 3.2 MB gather window L2-resident)
    k_agg<<<NBKT, 512, 0, stream>>>(bucketBase, tmp, hs1a, dis,
                                    b1, g1, be1, m1, v1, x1buf, 0);
    k_agg<<<NBKT, 512, 0, stream>>>(bucketBase, tmp, hs1b, dis,
                                    b1 + 8, g1 + 8, be1 + 8, m1 + 8, v1 + 8, x1buf, 8);
    k_x1w2<<<N / 16, 256, 0, stream>>>(x1buf, W2, dis, hs2a, hs2b);

    // layer 2
    k_agg<<<NBKT, 512, 0, stream>>>(bucketBase, tmp, hs2a, dis,
                                    b2, g2, be2, m2, v2, x2buf, 0);
    k_agg<<<NBKT, 512, 0, stream>>>(bucketBase, tmp, hs2b, dis,
                                    b2 + 8, g2 + 8, be2 + 8, m2 + 8, v2 + 8, x2buf, 8);

    k_pool<<<NB, 256, 0, stream>>>(x2buf, batch, gmaxT, gsum, gcnt);
    k_head<<<(G + 255) / 256, 256, 0, stream>>>(gmaxT, gsum, gcnt, Wb, bb, Wm, bm, out);
}

// Round 7
// 700.962 us; speedup vs baseline: 2.4902x; 2.4902x over previous
//
#include <hip/hip_runtime.h>
#include <math.h>

#define N   200000
#define E   6400000
#define IN_ 128
#define D   16
#define G   1024
#define BNEPS 1e-5f

#define BSH   7                      // 128 cols per bucket
#define BMSK  127
#define NBKT  1563                   // ceil(N / 128)
#define CH    8192                   // edges per k_bin block
#define BINB  782                    // ceil(E / CH)

typedef _Float16 f16;
typedef __attribute__((ext_vector_type(8))) _Float16 f16x8;
typedef __attribute__((ext_vector_type(4))) float f32x4;

// ---------- helpers ----------
__device__ __forceinline__ unsigned f2ord(float f) {
    unsigned b = __float_as_uint(f);
    return (b & 0x80000000u) ? ~b : (b | 0x80000000u);
}
__device__ __forceinline__ float ord2f(unsigned u) {
    return __uint_as_float((u & 0x80000000u) ? (u & 0x7FFFFFFFu) : ~u);
}

// ---------- bucket histogram ----------
__global__ __launch_bounds__(256) void k_hist(const int* __restrict__ col,
                                              unsigned* __restrict__ bucketCnt) {
    __shared__ unsigned h[NBKT];
    for (int i = threadIdx.x; i < NBKT; i += 256) h[i] = 0u;
    __syncthreads();
    int stride = gridDim.x * 256;
    for (int e = blockIdx.x * 256 + threadIdx.x; e < E; e += stride)
        atomicAdd(&h[col[e] >> BSH], 1u);
    __syncthreads();
    for (int i = threadIdx.x; i < NBKT; i += 256)
        if (h[i]) atomicAdd(&bucketCnt[i], h[i]);
}

// ---------- scan bucket counts (512 thr x 4 contiguous slots) ----------
__global__ __launch_bounds__(512) void k_bscan(const unsigned* __restrict__ bucketCnt,
                                               unsigned* __restrict__ bucketBase,
                                               unsigned* __restrict__ cursorB,
                                               unsigned* __restrict__ rowptr) {
    __shared__ unsigned bsum[512];
    int t = threadIdx.x;
    int base4 = t * 4;
    unsigned v[4], s = 0;
#pragma unroll
    for (int q = 0; q < 4; q++) {
        v[q] = (base4 + q < NBKT) ? bucketCnt[base4 + q] : 0u;
        s += v[q];
    }
    bsum[t] = s;
    __syncthreads();
    for (int off = 1; off < 512; off <<= 1) {
        unsigned x = (t >= off) ? bsum[t - off] : 0u;
        __syncthreads();
        bsum[t] += x;
        __syncthreads();
    }
    unsigned run = bsum[t] - s;   // exclusive
#pragma unroll
    for (int q = 0; q < 4; q++) {
        int b = base4 + q;
        if (b <= NBKT) { bucketBase[b] = run; cursorB[b] = run; }
        run += v[q];
    }
    if (t == 0) rowptr[N] = E;
}

// ---------- phase 1: bin edges by 128-col bucket ----------
// packed record: src (18 bits) | col_low7 << 18
__global__ __launch_bounds__(512) void k_bin(const int* __restrict__ row,
                                             const int* __restrict__ col,
                                             unsigned* __restrict__ cursorB,
                                             unsigned* __restrict__ tmp) {
    __shared__ unsigned hist[NBKT];    // counts (kept for copy-out)
    __shared__ unsigned lbase[NBKT];
    __shared__ unsigned lcur[NBKT];
    __shared__ unsigned gbase[NBKT];
    __shared__ unsigned bsum[512];
    __shared__ unsigned sbuf[CH];      // 32 KB
    int tid = threadIdx.x;
    int base = blockIdx.x * CH;
    int cnt = min(CH, E - base);
    for (int i = tid; i < NBKT; i += 512) hist[i] = 0u;
    __syncthreads();
    for (int i = tid; i < cnt; i += 512)
        atomicAdd(&hist[col[base + i] >> BSH], 1u);
    __syncthreads();
    // scan over NBKT: 4 contiguous slots per thread
    int base4 = tid * 4;
    unsigned v[4], s = 0;
#pragma unroll
    for (int q = 0; q < 4; q++) {
        v[q] = (base4 + q < NBKT) ? hist[base4 + q] : 0u;
        s += v[q];
    }
    bsum[tid] = s;
    __syncthreads();
    for (int off = 1; off < 512; off <<= 1) {
        unsigned x = (tid >= off) ? bsum[tid - off] : 0u;
        __syncthreads();
        bsum[tid] += x;
        __syncthreads();
    }
    unsigned run = bsum[tid] - s;
#pragma unroll
    for (int q = 0; q < 4; q++) {
        int b = base4 + q;
        if (b < NBKT) {
            lbase[b] = run;
            lcur[b] = run;
            if (v[q]) gbase[b] = atomicAdd(&cursorB[b], v[q]);
        }
        run += v[q];
    }
    __syncthreads();
    // scatter records into LDS grouped by bucket
    for (int i = tid; i < cnt; i += 512) {
        int c = col[base + i];
        int r = row[base + i];
        int b = c >> BSH;
        unsigned p = atomicAdd(&lcur[b], 1u);
        sbuf[p] = (unsigned)r | ((unsigned)(c & BMSK) << 18);
    }
    __syncthreads();
    // bucket-major coalesced-run copy-out: one wave per bucket
    int wv = tid >> 6, ln = tid & 63;
    for (int b = wv; b < NBKT; b += 8) {
        unsigned l0 = lbase[b], l1 = l0 + hist[b], gb = gbase[b];
        for (unsigned i2 = l0 + ln; i2 < l1; i2 += 64)
            tmp[gb + (i2 - l0)] = sbuf[i2];
    }
}

// ---------- phase 2: per-bucket (128 cols) counting sort -> srcA, rowptr, dis ----------
__global__ __launch_bounds__(512) void k_bsort(const unsigned* __restrict__ bucketBase,
                                               const unsigned* __restrict__ tmp,
                                               unsigned* __restrict__ rowptr,
                                               float* __restrict__ dis,
                                               int* __restrict__ srcA) {
    __shared__ unsigned cnt[128];
    __shared__ unsigned sc[128];
    __shared__ unsigned lcur[128];
    int tid = threadIdx.x;
    int b = blockIdx.x;
    unsigned s0 = bucketBase[b], s1 = bucketBase[b + 1];
    if (tid < 128) cnt[tid] = 0u;
    __syncthreads();
    for (unsigned i = s0 + tid; i < s1; i += 512) {
        unsigned rec = __builtin_nontemporal_load(tmp + i);
        atomicAdd(&cnt[rec >> 18], 1u);
    }
    __syncthreads();
    if (tid < 128) sc[tid] = cnt[tid];
    __syncthreads();
    for (int off = 1; off < 128; off <<= 1) {
        unsigned x = 0;
        if (tid < 128 && tid >= off) x = sc[tid - off];
        __syncthreads();
        if (tid < 128) sc[tid] += x;
        __syncthreads();
    }
    if (tid < 128) {
        unsigned excl = sc[tid] - cnt[tid];
        int c = (b << BSH) + tid;
        if (c < N) {
            rowptr[c] = s0 + excl;
            dis[c] = rsqrtf((float)cnt[tid] + 1.0f);
        }
        lcur[tid] = s0 + excl;
    }
    __syncthreads();
    for (unsigned i = s0 + tid; i < s1; i += 512) {
        unsigned rec = __builtin_nontemporal_load(tmp + i);
        unsigned pos = atomicAdd(&lcur[rec >> 18], 1u);
        srcA[pos] = (int)(rec & 0x3FFFFu);
    }
}

// ---------- hs1 = f16((x @ W1) * dis) via MFMA, split into two N x 8 halves ----------
__global__ __launch_bounds__(256) void k_gemm1(const float* __restrict__ x,
                                               const float* __restrict__ W1,
                                               const float* __restrict__ dis,
                                               f16* __restrict__ hsA,
                                               f16* __restrict__ hsB) {
    __shared__ f16 Wh[IN_ * D];
    int tid = threadIdx.x;
    for (int i = tid; i < IN_ * D; i += 256) Wh[i] = (f16)W1[i];
    __syncthreads();
    int lane = tid & 63;
    int wave = tid >> 6;
    int m = lane & 15, quad = lane >> 4;
    f16x8 bfrag[4];
#pragma unroll
    for (int s = 0; s < 4; s++)
#pragma unroll
        for (int jj = 0; jj < 8; jj++)
            bfrag[s][jj] = Wh[(s * 32 + quad * 8 + jj) * D + m];
    f16* outp = (m < 8) ? hsA : hsB;
    int mo = m & 7;
    int gwave = blockIdx.x * 4 + wave;
    int nwaves = gridDim.x * 4;
    const int ntiles = N / 16;
    for (int t = gwave; t < ntiles; t += nwaves) {
        int n0 = t * 16;
        const float* xrow = x + (size_t)(n0 + m) * IN_ + quad * 8;
        f32x4 acc = {0.f, 0.f, 0.f, 0.f};
#pragma unroll
        for (int s = 0; s < 4; s++) {
            float4 lo = *(const float4*)(xrow + s * 32);
            float4 hi = *(const float4*)(xrow + s * 32 + 4);
            f16x8 a;
            a[0] = (f16)lo.x; a[1] = (f16)lo.y; a[2] = (f16)lo.z; a[3] = (f16)lo.w;
            a[4] = (f16)hi.x; a[5] = (f16)hi.y; a[6] = (f16)hi.z; a[7] = (f16)hi.w;
            acc = __builtin_amdgcn_mfma_f32_16x16x32_f16(a, bfrag[s], acc, 0, 0, 0);
        }
#pragma unroll
        for (int r = 0; r < 4; r++) {
            int rowi = n0 + quad * 4 + r;
            outp[(size_t)rowi * 8 + mo] = (f16)(acc[r] * dis[rowi]);
        }
    }
}

// ---------- CSR gather over one 8-feature half + epilogue (ReLU+BN), out at col*16+hoff ----------
// 8 lanes per node; lane l loads whole 16B half-rows of its edges, butterfly-reduce, lane l keeps feature l.
__global__ __launch_bounds__(256) void k_gath(const unsigned* __restrict__ rowptr,
                                              const int* __restrict__ srcA,
                                              const f16* __restrict__ hsplit,
                                              const float* __restrict__ dis,
                                              const float* __restrict__ bp,
                                              const float* __restrict__ gp,
                                              const float* __restrict__ bep,
                                              const float* __restrict__ mp,
                                              const float* __restrict__ vp,
                                              f16* __restrict__ out16,
                                              int hoff) {
    int tid = threadIdx.x;
    int i = blockIdx.x * 32 + (tid >> 3);   // node; grid = N/32 exact
    int l = tid & 7;
    unsigned start = rowptr[i], end = rowptr[i + 1];
    float acc[8] = {0.f, 0.f, 0.f, 0.f, 0.f, 0.f, 0.f, 0.f};
    for (unsigned idx = start + l; idx < end; idx += 8) {
        int src = srcA[idx];
        f16x8 v = *(const f16x8*)(hsplit + ((size_t)src << 3));
#pragma unroll
        for (int f = 0; f < 8; f++) acc[f] += (float)v[f];
    }
    // butterfly within the 8-lane group
#pragma unroll
    for (int m = 1; m <= 4; m <<= 1) {
#pragma unroll
        for (int f = 0; f < 8; f++) acc[f] += __shfl_xor(acc[f], m, 8);
    }
    float s = 0.f;
#pragma unroll
    for (int f = 0; f < 8; f++) if (l == f) s = acc[f];
    s += (float)hsplit[((size_t)i << 3) + l];   // self-loop (dis folded)
    float di = dis[i];
    float tt = fmaxf(di * s + bp[l], 0.f);
    float sc = gp[l] * rsqrtf(vp[l] + BNEPS);
    out16[((size_t)i << 4) + hoff + l] = (f16)(tt * sc + (bep[l] - mp[l] * sc));
}

// ---------- hs2 = f16((x1 @ W2) * dis), split halves ----------
__global__ __launch_bounds__(256) void k_x1w2(const f16* __restrict__ x1,
                                              const float* __restrict__ W2,
                                              const float* __restrict__ dis,
                                              f16* __restrict__ hsA,
                                              f16* __restrict__ hsB) {
    __shared__ float W2s[D * D];
    int tid = threadIdx.x;
    if (tid < D * D) W2s[tid] = W2[tid];
    __syncthreads();
    int i = blockIdx.x * 16 + (tid >> 4);
    int j = tid & 15;
    float xv = (float)x1[(size_t)i * 16 + j];
    float acc = 0.f;
#pragma unroll
    for (int kk = 0; kk < D; kk++) {
        float v = __shfl(xv, kk, 16);
        acc += v * W2s[kk * D + j];
    }
    f16 r = (f16)(acc * dis[i]);
    if (j < 8) hsA[(size_t)i * 8 + j] = r;
    else       hsB[(size_t)i * 8 + (j - 8)] = r;
}

// ---------- pooling ----------
__global__ __launch_bounds__(256) void k_pool(const f16* __restrict__ x2,
                                              const int* __restrict__ batch,
                                              unsigned* __restrict__ gmaxT,
                                              float* __restrict__ gsum,
                                              unsigned* __restrict__ gcnt) {
    __shared__ unsigned smax[32 * D];
    __shared__ float ssum[32 * D];
    __shared__ unsigned scnt[32];
    int tid = threadIdx.x;
    for (int s = tid; s < 32 * D; s += 256) { smax[s] = 0u; ssum[s] = 0.f; }
    if (tid < 32) scnt[tid] = 0u;
    __syncthreads();
    int n = blockIdx.x * 256 + tid;
    int g0 = batch[blockIdx.x * 256];
    if (n < N) {
        int lg = batch[n] - g0;
        const f16* xp = x2 + (size_t)n * D;
        if (lg < 32) {
            atomicAdd(&scnt[lg], 1u);
#pragma unroll
            for (int j = 0; j < D; j++) {
                float v = (float)xp[j];
                atomicMax(&smax[lg * D + j], f2ord(v));
                atomicAdd(&ssum[lg * D + j], v);
            }
        } else {
            int g = batch[n];
            atomicAdd(&gcnt[g], 1u);
#pragma unroll
            for (int j = 0; j < D; j++) {
                float v = (float)xp[j];
                atomicMax(&gmaxT[(size_t)g * D + j], f2ord(v));
                atomicAdd(&gsum[(size_t)g * D + j], v);
            }
        }
    }
    __syncthreads();
    for (int s = tid; s < 32 * D; s += 256) {
        int slot = s >> 4, j = s & 15;
        if (scnt[slot] > 0u) {
            int g = g0 + slot;
            atomicMax(&gmaxT[(size_t)g * D + j], smax[s]);
            atomicAdd(&gsum[(size_t)g * D + j], ssum[s]);
            if (j == 0) atomicAdd(&gcnt[g], scnt[slot]);
        }
    }
}

// ---------- head ----------
__global__ __launch_bounds__(256) void k_head(const unsigned* __restrict__ gmaxT,
                                              const float* __restrict__ gsum,
                                              const unsigned* __restrict__ gcnt,
                                              const float* __restrict__ Wb,
                                              const float* __restrict__ bb,
                                              const float* __restrict__ Wm,
                                              const float* __restrict__ bm,
                                              float* __restrict__ out) {
    __shared__ float Wbs[32 * 16];
    __shared__ float bbs[16], Wms[16];
    __shared__ float bm0;
    int tid = threadIdx.x;
    for (int i = tid; i < 32 * 16; i += 256) Wbs[i] = Wb[i];
    if (tid < 16) { bbs[tid] = bb[tid]; Wms[tid] = Wm[tid]; }
    if (tid == 0) bm0 = bm[0];
    __syncthreads();
    int g = blockIdx.x * 256 + tid;
    if (g >= G) return;
    float in[32];
    float inv = 1.0f / (float)gcnt[g];
#pragma unroll
    for (int j = 0; j < D; j++) {
        in[j] = ord2f(gmaxT[(size_t)g * D + j]);
        in[16 + j] = gsum[(size_t)g * D + j] * inv;
    }
    float z = bm0;
#pragma unroll
    for (int j = 0; j < 16; j++) {
        float acc = bbs[j];
#pragma unroll
        for (int k = 0; k < 32; k++) acc += in[k] * Wbs[k * 16 + j];
        acc = fmaxf(acc, 0.f);
        z += acc * Wms[j];
    }
    out[g] = 1.0f / (1.0f + expf(-z));
}

extern "C" void kernel_launch(void* const* d_in, const int* in_sizes, int n_in,
                              void* d_out, int out_size, void* d_ws, size_t ws_size,
                              hipStream_t stream) {
    const float* x   = (const float*)d_in[0];
    const int* ei    = (const int*)d_in[1];
    const int* rowp  = ei;
    const int* colp  = ei + E;
    const int* batch = (const int*)d_in[2];
    const float* W1  = (const float*)d_in[3];
    const float* b1  = (const float*)d_in[4];
    const float* g1  = (const float*)d_in[5];
    const float* be1 = (const float*)d_in[6];
    const float* m1  = (const float*)d_in[7];
    const float* v1  = (const float*)d_in[8];
    const float* W2  = (const float*)d_in[9];
    const float* b2  = (const float*)d_in[10];
    const float* g2  = (const float*)d_in[11];
    const float* be2 = (const float*)d_in[12];
    const float* m2  = (const float*)d_in[13];
    const float* v2  = (const float*)d_in[14];
    const float* Wb  = (const float*)d_in[15];
    const float* bb  = (const float*)d_in[16];
    const float* Wm  = (const float*)d_in[17];
    const float* bm  = (const float*)d_in[18];
    float* out = (float*)d_out;

    char* ws = (char*)d_ws;
    // layout (bytes):
    int*      srcA  = (int*)     (ws);               // E i32 [0, 25.6M) — live all run
    unsigned* tmp   = (unsigned*)(ws + 25600000);    // E u32 [25.6M, 51.2M) — dead after k_bsort
    f16* hs1a  = (f16*)(ws + 25600000);              // N*8 f16 (3.2 MB) — overlays tmp
    f16* hs1b  = (f16*)(ws + 28800000);
    f16* hs2a  = (f16*)(ws + 32000000);
    f16* hs2b  = (f16*)(ws + 35200000);
    f16* x1buf = (f16*)(ws + 38400000);              // N*16 f16 (6.4 MB)
    unsigned* rowptr = (unsigned*)(ws + 51200000);   // (N+1) u32
    float*    dis    = (float*)   (ws + 52000016);   // N f32
    unsigned* bucketCnt  = (unsigned*)(ws + 52800016);  // NBKT+1
    unsigned* bucketBase = (unsigned*)(ws + 52806288);  // NBKT+1
    unsigned* cursorB    = (unsigned*)(ws + 52812560);  // NBKT+1
    unsigned* gmaxT = (unsigned*)(ws + 52818832);    // G*D
    float*    gsum  = (float*)   (ws + 52884368);    // G*D
    unsigned* gcnt  = (unsigned*)(ws + 52949904);    // G
    f16* x2buf = x1buf;   // x1 consumed by k_x1w2 before layer-2 gathers write x2

    const int NB = (N + 255) / 256;

    hipMemsetAsync(bucketCnt, 0, (NBKT + 1) * 4, stream);
    hipMemsetAsync(gmaxT, 0, (size_t)G * D * 4, stream);
    hipMemsetAsync(gsum, 0, (size_t)G * D * 4, stream);
    hipMemsetAsync(gcnt, 0, (size_t)G * 4, stream);

    k_hist<<<512, 256, 0, stream>>>(colp, bucketCnt);
    k_bscan<<<1, 512, 0, stream>>>(bucketCnt, bucketBase, cursorB, rowptr);
    k_bin<<<BINB, 512, 0, stream>>>(rowp, colp, cursorB, tmp);
    k_bsort<<<NBKT, 512, 0, stream>>>(bucketBase, tmp, rowptr, dis, srcA);

    k_gemm1<<<512, 256, 0, stream>>>(x, W1, dis, hs1a, hs1b);

    // layer 1: two L2-resident half passes
    k_gath<<<N / 32, 256, 0, stream>>>(rowptr, srcA, hs1a, dis,
                                       b1, g1, be1, m1, v1, x1buf, 0);
    k_gath<<<N / 32, 256, 0, stream>>>(rowptr, srcA, hs1b, dis,
                                       b1 + 8, g1 + 8, be1 + 8, m1 + 8, v1 + 8, x1buf, 8);
    k_x1w2<<<N / 16, 256, 0, stream>>>(x1buf, W2, dis, hs2a, hs2b);

    // layer 2
    k_gath<<<N / 32, 256, 0, stream>>>(rowptr, srcA, hs2a, dis,
                                       b2, g2, be2, m2, v2, x2buf, 0);
    k_gath<<<N / 32, 256, 0, stream>>>(rowptr, srcA, hs2b, dis,
                                       b2 + 8, g2 + 8, be2 + 8, m2 + 8, v2 + 8, x2buf, 8);

    k_pool<<<NB, 256, 0, stream>>>(x2buf, batch, gmaxT, gsum, gcnt);
    k_head<<<(G + 255) / 256, 256, 0, stream>>>(gmaxT, gsum, gcnt, Wb, bb, Wm, bm, out);
}

// Round 8
// 622.037 us; speedup vs baseline: 2.8062x; 1.1269x over previous
//
#include <hip/hip_runtime.h>
#include <math.h>

#define N   200000
#define E   6400000
#define IN_ 128
#define D   16
#define G   1024
#define BNEPS 1e-5f

#define BSH   9                      // 512 cols per bucket
#define BMSK  511
#define NBKT  391                    // ceil(N / 512)
#define CH    8192                   // edges per k_bin block
#define BINB  782                    // ceil(E / CH)
#define SSEG  4                      // segments per bucket in the sort

typedef _Float16 f16;
typedef __attribute__((ext_vector_type(8))) _Float16 f16x8;
typedef __attribute__((ext_vector_type(4))) float f32x4;

// ---------- helpers ----------
__device__ __forceinline__ unsigned f2ord(float f) {
    unsigned b = __float_as_uint(f);
    return (b & 0x80000000u) ? ~b : (b | 0x80000000u);
}
__device__ __forceinline__ float ord2f(unsigned u) {
    return __uint_as_float((u & 0x80000000u) ? (u & 0x7FFFFFFFu) : ~u);
}

// ---------- bucket histogram ----------
__global__ __launch_bounds__(256) void k_hist(const int* __restrict__ col,
                                              unsigned* __restrict__ bucketCnt) {
    __shared__ unsigned h[NBKT];
    for (int i = threadIdx.x; i < NBKT; i += 256) h[i] = 0u;
    __syncthreads();
    int stride = gridDim.x * 256;
    for (int e = blockIdx.x * 256 + threadIdx.x; e < E; e += stride)
        atomicAdd(&h[col[e] >> BSH], 1u);
    __syncthreads();
    for (int i = threadIdx.x; i < NBKT; i += 256)
        if (h[i]) atomicAdd(&bucketCnt[i], h[i]);
}

// ---------- scan bucket counts ----------
__global__ __launch_bounds__(512) void k_bscan(const unsigned* __restrict__ bucketCnt,
                                               unsigned* __restrict__ bucketBase,
                                               unsigned* __restrict__ cursorB,
                                               unsigned* __restrict__ rowptr) {
    __shared__ unsigned s[512];
    int t = threadIdx.x;
    s[t] = (t < NBKT) ? bucketCnt[t] : 0u;
    __syncthreads();
    for (int off = 1; off < 512; off <<= 1) {
        unsigned v = (t >= off) ? s[t - off] : 0u;
        __syncthreads();
        s[t] += v;
        __syncthreads();
    }
    unsigned excl = (t > 0) ? s[t - 1] : 0u;
    if (t <= NBKT) {
        bucketBase[t] = excl;
        cursorB[t] = excl;
    }
    if (t == 0) rowptr[N] = E;
}

// ---------- phase 1: bin edges by 512-col bucket (r5 version, measured good) ----------
// packed record: src (18 bits) | col_low9 << 18
__global__ __launch_bounds__(512) void k_bin(const int* __restrict__ row,
                                             const int* __restrict__ col,
                                             unsigned* __restrict__ cursorB,
                                             unsigned* __restrict__ tmp) {
    __shared__ unsigned hist[512];   // becomes lbase after scan
    __shared__ unsigned offs[512];   // inclusive scan
    __shared__ unsigned lcur[512];
    __shared__ unsigned gbase[512];
    __shared__ unsigned sbuf[CH];    // 32 KB
    int tid = threadIdx.x;
    int base = blockIdx.x * CH;
    int cnt = min(CH, E - base);
    hist[tid] = 0u;
    __syncthreads();
    for (int i = tid; i < cnt; i += 512)
        atomicAdd(&hist[col[base + i] >> BSH], 1u);
    __syncthreads();
    offs[tid] = hist[tid];
    __syncthreads();
    for (int off = 1; off < 512; off <<= 1) {
        unsigned v = (tid >= off) ? offs[tid - off] : 0u;
        __syncthreads();
        offs[tid] += v;
        __syncthreads();
    }
    unsigned lb = (tid > 0) ? offs[tid - 1] : 0u;
    unsigned c0 = offs[tid] - lb;
    lcur[tid] = lb;
    hist[tid] = lb;   // hist now holds lbase
    if (tid < NBKT && c0) gbase[tid] = atomicAdd(&cursorB[tid], c0);
    __syncthreads();
    for (int i = tid; i < cnt; i += 512) {
        int c = col[base + i];
        int r = row[base + i];
        int b = c >> BSH;
        unsigned p = atomicAdd(&lcur[b], 1u);
        sbuf[p] = (unsigned)r | ((unsigned)(c & BMSK) << 18);
    }
    __syncthreads();
    // bucket-major coalesced-run copy-out: one wave per bucket (runs avg ~21)
    int wv = tid >> 6, ln = tid & 63;
    for (int b = wv; b < NBKT; b += 8) {
        unsigned l0 = hist[b], l1 = offs[b], gb = gbase[b];
        for (unsigned i2 = l0 + ln; i2 < l1; i2 += 64)
            tmp[gb + (i2 - l0)] = sbuf[i2];
    }
}

// ---------- phase 2a: per-(bucket,segment) column histogram ----------
__global__ __launch_bounds__(256) void k_colcnt(const unsigned* __restrict__ bucketBase,
                                                const unsigned* __restrict__ tmp,
                                                unsigned* __restrict__ seghist) {
    __shared__ unsigned cnt[512];
    int tid = threadIdx.x;
    int blk = blockIdx.x;
    int b = blk >> 2, s = blk & 3;
    unsigned s0 = bucketBase[b], s1 = bucketBase[b + 1];
    unsigned len = s1 - s0;
    unsigned l4 = (len + SSEG - 1) / SSEG;
    unsigned a0 = s0 + s * l4;
    unsigned a1 = min(a0 + l4, s1);
    cnt[tid] = 0u; cnt[tid + 256] = 0u;
    __syncthreads();
    for (unsigned i = a0 + tid; i < a1; i += 256) {
        unsigned rec = __builtin_nontemporal_load(tmp + i);
        atomicAdd(&cnt[rec >> 18], 1u);
    }
    __syncthreads();
    seghist[(size_t)blk * 512 + tid] = cnt[tid];
    seghist[(size_t)blk * 512 + tid + 256] = cnt[tid + 256];
}

// ---------- phase 2b: per-bucket column scan -> rowptr, dis, per-seg bases (in-place) ----------
__global__ __launch_bounds__(512) void k_colscan(const unsigned* __restrict__ bucketBase,
                                                 unsigned* __restrict__ seghist,
                                                 unsigned* __restrict__ rowptr,
                                                 float* __restrict__ dis) {
    __shared__ unsigned tot[512];
    int c = threadIdx.x;
    int b = blockIdx.x;
    size_t base = (size_t)b * 4 * 512;
    unsigned v0 = seghist[base + 0 * 512 + c];
    unsigned v1 = seghist[base + 1 * 512 + c];
    unsigned v2 = seghist[base + 2 * 512 + c];
    unsigned v3 = seghist[base + 3 * 512 + c];
    unsigned t = v0 + v1 + v2 + v3;
    tot[c] = t;
    __syncthreads();
    for (int off = 1; off < 512; off <<= 1) {
        unsigned x = (c >= off) ? tot[c - off] : 0u;
        __syncthreads();
        tot[c] += x;
        __syncthreads();
    }
    unsigned excl = tot[c] - t;
    unsigned b0 = bucketBase[b] + excl;
    int colg = (b << BSH) + c;
    if (colg < N) {
        rowptr[colg] = b0;
        dis[colg] = rsqrtf((float)t + 1.0f);
    }
    seghist[base + 0 * 512 + c] = b0;
    seghist[base + 1 * 512 + c] = b0 + v0;
    seghist[base + 2 * 512 + c] = b0 + v0 + v1;
    seghist[base + 3 * 512 + c] = b0 + v0 + v1 + v2;
}

// ---------- phase 2c: segment-local placement with exact bases ----------
__global__ __launch_bounds__(256) void k_place(const unsigned* __restrict__ bucketBase,
                                               const unsigned* __restrict__ tmp,
                                               const unsigned* __restrict__ segbase,
                                               int* __restrict__ srcA) {
    __shared__ unsigned cur[512];
    int tid = threadIdx.x;
    int blk = blockIdx.x;
    int b = blk >> 2, s = blk & 3;
    unsigned s0 = bucketBase[b], s1 = bucketBase[b + 1];
    unsigned len = s1 - s0;
    unsigned l4 = (len + SSEG - 1) / SSEG;
    unsigned a0 = s0 + s * l4;
    unsigned a1 = min(a0 + l4, s1);
    cur[tid] = segbase[(size_t)blk * 512 + tid];
    cur[tid + 256] = segbase[(size_t)blk * 512 + tid + 256];
    __syncthreads();
    for (unsigned i = a0 + tid; i < a1; i += 256) {
        unsigned rec = __builtin_nontemporal_load(tmp + i);
        unsigned pos = atomicAdd(&cur[rec >> 18], 1u);
        srcA[pos] = (int)(rec & 0x3FFFFu);
    }
}

// ---------- hs1 = f16((x @ W1) * dis) via MFMA 16x16x32 f16 ----------
__global__ __launch_bounds__(256) void k_gemm1(const float* __restrict__ x,
                                               const float* __restrict__ W1,
                                               const float* __restrict__ dis,
                                               f16* __restrict__ hs) {
    __shared__ f16 Wh[IN_ * D];
    int tid = threadIdx.x;
    for (int i = tid; i < IN_ * D; i += 256) Wh[i] = (f16)W1[i];
    __syncthreads();
    int lane = tid & 63;
    int wave = tid >> 6;
    int m = lane & 15, quad = lane >> 4;
    f16x8 bfrag[4];
#pragma unroll
    for (int s = 0; s < 4; s++)
#pragma unroll
        for (int jj = 0; jj < 8; jj++)
            bfrag[s][jj] = Wh[(s * 32 + quad * 8 + jj) * D + m];
    int gwave = blockIdx.x * 4 + wave;
    int nwaves = gridDim.x * 4;
    const int ntiles = N / 16;
    for (int t = gwave; t < ntiles; t += nwaves) {
        int n0 = t * 16;
        const float* xrow = x + (size_t)(n0 + m) * IN_ + quad * 8;
        f32x4 acc = {0.f, 0.f, 0.f, 0.f};
#pragma unroll
        for (int s = 0; s < 4; s++) {
            float4 lo = *(const float4*)(xrow + s * 32);
            float4 hi = *(const float4*)(xrow + s * 32 + 4);
            f16x8 a;
            a[0] = (f16)lo.x; a[1] = (f16)lo.y; a[2] = (f16)lo.z; a[3] = (f16)lo.w;
            a[4] = (f16)hi.x; a[5] = (f16)hi.y; a[6] = (f16)hi.z; a[7] = (f16)hi.w;
            acc = __builtin_amdgcn_mfma_f32_16x16x32_f16(a, bfrag[s], acc, 0, 0, 0);
        }
#pragma unroll
        for (int r = 0; r < 4; r++) {
            int rowi = n0 + quad * 4 + r;
            hs[(size_t)rowi * D + m] = (f16)(acc[r] * dis[rowi]);
        }
    }
}

// ---------- wide gather core (r5, measured): 16 lanes/node, f16x8 loads ----------
__device__ __forceinline__ float gather_row_sum(const unsigned* __restrict__ rowptr,
                                                const int* __restrict__ srcA,
                                                const f16* __restrict__ hs,
                                                int i, int j, float seed) {
    unsigned start = rowptr[i], end = rowptr[i + 1];
    unsigned len = end - start;
    unsigned nfull = len & ~7u;
    int es = j >> 1;          // edge slot 0..7
    int half = j & 1;         // which 8-feature half
    float acc[8] = {0.f, 0.f, 0.f, 0.f, 0.f, 0.f, 0.f, 0.f};
    for (unsigned off = 0; off < nfull; off += 8) {
        int idx = srcA[start + off + (j & 7)];
        int src = __shfl(idx, es, 16);
        const f16x8 v = *(const f16x8*)(hs + ((size_t)src << 4) + (half << 3));
#pragma unroll
        for (int k = 0; k < 8; k++) acc[k] += (float)v[k];
    }
#pragma unroll
    for (int mask = 2; mask <= 8; mask <<= 1) {
#pragma unroll
        for (int k = 0; k < 8; k++) acc[k] += __shfl_xor(acc[k], mask, 16);
    }
    float x = 0.f;
    int srcl = j >> 3;
#pragma unroll
    for (int k = 0; k < 8; k++) {
        float vk = __shfl(acc[k], srcl, 16);
        if ((j & 7) == k) x = vk;
    }
    float xt = seed;
    for (unsigned e = start + nfull; e < end; e++) {
        int src = srcA[e];
        xt += (float)hs[((size_t)src << 4) + j];
    }
    return x + xt;
}

// ---------- layer1 gather + BN1/ReLU + GEMM2 ----------
__global__ __launch_bounds__(256) void k_gather1(const unsigned* __restrict__ rowptr,
                                                 const int* __restrict__ srcA,
                                                 const float* __restrict__ dis,
                                                 const f16* __restrict__ hs1,
                                                 const float* __restrict__ b1,
                                                 const float* __restrict__ g1,
                                                 const float* __restrict__ be1,
                                                 const float* __restrict__ m1,
                                                 const float* __restrict__ v1,
                                                 const float* __restrict__ W2,
                                                 f16* __restrict__ hs2) {
    __shared__ float W2s[D * D];
    int tid = threadIdx.x;
    if (tid < D * D) W2s[tid] = W2[tid];
    __syncthreads();
    int i = blockIdx.x * 16 + (tid >> 4);
    int j = tid & 15;
    float self = (float)hs1[((size_t)i << 4) + j];
    float sum = gather_row_sum(rowptr, srcA, hs1, i, j, self);
    float di = dis[i];
    float tt = di * sum + b1[j];
    tt = fmaxf(tt, 0.f);
    float sc = g1[j] * rsqrtf(v1[j] + BNEPS);
    float x1 = (tt - m1[j]) * sc + be1[j];
    float acc = 0.f;
#pragma unroll
    for (int kk = 0; kk < D; kk++) {
        float v = __shfl(x1, kk, 16);
        acc += v * W2s[kk * D + j];
    }
    hs2[((size_t)i << 4) + j] = (f16)(acc * di);
}

// ---------- layer2 gather + BN2/ReLU ----------
__global__ __launch_bounds__(256) void k_gather2(const unsigned* __restrict__ rowptr,
                                                 const int* __restrict__ srcA,
                                                 const float* __restrict__ dis,
                                                 const f16* __restrict__ hs2,
                                                 const float* __restrict__ b2,
                                                 const float* __restrict__ g2,
                                                 const float* __restrict__ be2,
                                                 const float* __restrict__ m2,
                                                 const float* __restrict__ v2,
                                                 f16* __restrict__ x2) {
    int tid = threadIdx.x;
    int i = blockIdx.x * 16 + (tid >> 4);
    int j = tid & 15;
    float self = (float)hs2[((size_t)i << 4) + j];
    float sum = gather_row_sum(rowptr, srcA, hs2, i, j, self);
    float tt = dis[i] * sum + b2[j];
    tt = fmaxf(tt, 0.f);
    float sc = g2[j] * rsqrtf(v2[j] + BNEPS);
    x2[((size_t)i << 4) + j] = (f16)((tt - m2[j]) * sc + be2[j]);
}

// ---------- pooling ----------
__global__ __launch_bounds__(256) void k_pool(const f16* __restrict__ x2,
                                              const int* __restrict__ batch,
                                              unsigned* __restrict__ gmaxT,
                                              float* __restrict__ gsum,
                                              unsigned* __restrict__ gcnt) {
    __shared__ unsigned smax[32 * D];
    __shared__ float ssum[32 * D];
    __shared__ unsigned scnt[32];
    int tid = threadIdx.x;
    for (int s = tid; s < 32 * D; s += 256) { smax[s] = 0u; ssum[s] = 0.f; }
    if (tid < 32) scnt[tid] = 0u;
    __syncthreads();
    int n = blockIdx.x * 256 + tid;
    int g0 = batch[blockIdx.x * 256];
    if (n < N) {
        int lg = batch[n] - g0;
        const f16* xp = x2 + (size_t)n * D;
        if (lg < 32) {
            atomicAdd(&scnt[lg], 1u);
#pragma unroll
            for (int j = 0; j < D; j++) {
                float v = (float)xp[j];
                atomicMax(&smax[lg * D + j], f2ord(v));
                atomicAdd(&ssum[lg * D + j], v);
            }
        } else {
            int g = batch[n];
            atomicAdd(&gcnt[g], 1u);
#pragma unroll
            for (int j = 0; j < D; j++) {
                float v = (float)xp[j];
                atomicMax(&gmaxT[(size_t)g * D + j], f2ord(v));
                atomicAdd(&gsum[(size_t)g * D + j], v);
            }
        }
    }
    __syncthreads();
    for (int s = tid; s < 32 * D; s += 256) {
        int slot = s >> 4, j = s & 15;
        if (scnt[slot] > 0u) {
            int g = g0 + slot;
            atomicMax(&gmaxT[(size_t)g * D + j], smax[s]);
            atomicAdd(&gsum[(size_t)g * D + j], ssum[s]);
            if (j == 0) atomicAdd(&gcnt[g], scnt[slot]);
        }
    }
}

// ---------- head ----------
__global__ __launch_bounds__(256) void k_head(const unsigned* __restrict__ gmaxT,
                                              const float* __restrict__ gsum,
                                              const unsigned* __restrict__ gcnt,
                                              const float* __restrict__ Wb,
                                              const float* __restrict__ bb,
                                              const float* __restrict__ Wm,
                                              const float* __restrict__ bm,
                                              float* __restrict__ out) {
    __shared__ float Wbs[32 * 16];
    __shared__ float bbs[16], Wms[16];
    __shared__ float bm0;
    int tid = threadIdx.x;
    for (int i = tid; i < 32 * 16; i += 256) Wbs[i] = Wb[i];
    if (tid < 16) { bbs[tid] = bb[tid]; Wms[tid] = Wm[tid]; }
    if (tid == 0) bm0 = bm[0];
    __syncthreads();
    int g = blockIdx.x * 256 + tid;
    if (g >= G) return;
    float in[32];
    float inv = 1.0f / (float)gcnt[g];
#pragma unroll
    for (int j = 0; j < D; j++) {
        in[j] = ord2f(gmaxT[(size_t)g * D + j]);
        in[16 + j] = gsum[(size_t)g * D + j] * inv;
    }
    float z = bm0;
#pragma unroll
    for (int j = 0; j < 16; j++) {
        float acc = bbs[j];
#pragma unroll
        for (int k = 0; k < 32; k++) acc += in[k] * Wbs[k * 16 + j];
        acc = fmaxf(acc, 0.f);
        z += acc * Wms[j];
    }
    out[g] = 1.0f / (1.0f + expf(-z));
}

extern "C" void kernel_launch(void* const* d_in, const int* in_sizes, int n_in,
                              void* d_out, int out_size, void* d_ws, size_t ws_size,
                              hipStream_t stream) {
    const float* x   = (const float*)d_in[0];
    const int* ei    = (const int*)d_in[1];
    const int* rowp  = ei;
    const int* colp  = ei + E;
    const int* batch = (const int*)d_in[2];
    const float* W1  = (const float*)d_in[3];
    const float* b1  = (const float*)d_in[4];
    const float* g1  = (const float*)d_in[5];
    const float* be1 = (const float*)d_in[6];
    const float* m1  = (const float*)d_in[7];
    const float* v1  = (const float*)d_in[8];
    const float* W2  = (const float*)d_in[9];
    const float* b2  = (const float*)d_in[10];
    const float* g2  = (const float*)d_in[11];
    const float* be2 = (const float*)d_in[12];
    const float* m2  = (const float*)d_in[13];
    const float* v2  = (const float*)d_in[14];
    const float* Wb  = (const float*)d_in[15];
    const float* bb  = (const float*)d_in[16];
    const float* Wm  = (const float*)d_in[17];
    const float* bm  = (const float*)d_in[18];
    float* out = (float*)d_out;

    char* ws = (char*)d_ws;
    // layout (bytes):
    int*      srcA  = (int*)     (ws);               // E i32 [0, 25.6M) — live all run
    unsigned* tmp   = (unsigned*)(ws + 25600000);    // E u32 [25.6M, 51.2M) — dead after k_place
    f16* hs1   = (f16*)(ws + 25600000);              // N*16 f16 (6.4 MB) — overlays tmp after sort
    f16* hs2   = (f16*)(ws + 32000000);              // N*16 f16 (6.4 MB)
    unsigned* rowptr = (unsigned*)(ws + 51200000);   // (N+1) u32
    float*    dis    = (float*)   (ws + 52000016);   // N f32
    unsigned* bucketCnt  = (unsigned*)(ws + 52800016);  // NBKT+1
    unsigned* bucketBase = (unsigned*)(ws + 52801600);  // NBKT+1
    unsigned* cursorB    = (unsigned*)(ws + 52803200);  // NBKT+1
    unsigned* gmaxT = (unsigned*)(ws + 52804800);    // G*D u32
    float*    gsum  = (float*)   (ws + 52870336);    // G*D f32
    unsigned* gcnt  = (unsigned*)(ws + 52935872);    // G u32
    unsigned* seghist = (unsigned*)(ws + 52940032);  // NBKT*4*512 u32 (3.2 MB), reused as segbase
    f16* x2buf = hs1;   // hs1 dead after k_gather1

    const int NB = (N + 255) / 256;

    hipMemsetAsync(bucketCnt, 0, (NBKT + 1) * 4, stream);
    hipMemsetAsync(gmaxT, 0, (size_t)G * D * 4, stream);
    hipMemsetAsync(gsum, 0, (size_t)G * D * 4, stream);
    hipMemsetAsync(gcnt, 0, (size_t)G * 4, stream);

    k_hist<<<1024, 256, 0, stream>>>(colp, bucketCnt);
    k_bscan<<<1, 512, 0, stream>>>(bucketCnt, bucketBase, cursorB, rowptr);
    k_bin<<<BINB, 512, 0, stream>>>(rowp, colp, cursorB, tmp);
    k_colcnt<<<NBKT * SSEG, 256, 0, stream>>>(bucketBase, tmp, seghist);
    k_colscan<<<NBKT, 512, 0, stream>>>(bucketBase, seghist, rowptr, dis);
    k_place<<<NBKT * SSEG, 256, 0, stream>>>(bucketBase, tmp, seghist, srcA);

    k_gemm1<<<512, 256, 0, stream>>>(x, W1, dis, hs1);

    k_gather1<<<N / 16, 256, 0, stream>>>(rowptr, srcA, dis, hs1,
                                          b1, g1, be1, m1, v1, W2, hs2);
    k_gather2<<<N / 16, 256, 0, stream>>>(rowptr, srcA, dis, hs2,
                                          b2, g2, be2, m2, v2, x2buf);

    k_pool<<<NB, 256, 0, stream>>>(x2buf, batch, gmaxT, gsum, gcnt);
    k_head<<<(G + 255) / 256, 256, 0, stream>>>(gmaxT, gsum, gcnt, Wb, bb, Wm, bm, out);
}